// Round 1
// baseline (333.532 us; speedup 1.0000x reference)
//
#include <hip/hip_runtime.h>
#include <hip/hip_bf16.h>

#define N_ 32
#define C_ 64
#define H_ 128
#define W_ 128
#define HW_ (H_ * W_)
#define CHW_ (C_ * HW_)

#define XT_STRIDE 72           // halfs per row (144 B); chunks 0..7 hold c 0..63, +8 halfs tail pad
#define XT_ROWS 146            // rows = w + 9 for w in [-9, 137)
#define SMEM_HALFS (XT_ROWS * XT_STRIDE)   // 10512 halfs = 21024 B -> 7 blocks/CU

typedef __bf16 bf16x8 __attribute__((ext_vector_type(8)));
typedef float floatx4 __attribute__((ext_vector_type(4)));

__device__ inline unsigned short f2bf(float f) {
    __hip_bfloat16 h = __float2bfloat16(f);
    return *reinterpret_cast<unsigned short*>(&h);
}

// Pre-pack weights into MFMA fragment order (bf16).
// frag[kt][ot][lane] = W[o = ot*16 + (lane&15)][k = kt*32 + (lane>>4)*8 + i], k = t*64 + c.
// Same bytes serve as A-frag (m=o) or B-frag (n=o) — layout is role-symmetric.
__global__ void prepack_kernel(const float* __restrict__ Wc, uint4* __restrict__ Ap) {
    int idx = blockIdx.x * 256 + threadIdx.x;
    if (idx >= 14 * 4 * 64) return;
    int lane = idx & 63;
    int mt = (idx >> 6) & 3;
    int kt = idx >> 8;
    int m = mt * 16 + (lane & 15);
    int kbase = kt * 32 + (lane >> 4) * 8;
    unsigned int r[4];
    #pragma unroll
    for (int p = 0; p < 4; ++p) {
        unsigned int half[2];
        #pragma unroll
        for (int jj = 0; jj < 2; ++jj) {
            int k = kbase + 2 * p + jj;
            int t = k >> 6;
            int i = k & 63;
            half[jj] = f2bf(Wc[m * 448 + i * 7 + t]);
        }
        r[p] = half[0] | (half[1] << 16);
    }
    Ap[idx] = make_uint4(r[0], r[1], r[2], r[3]);
}

__global__ __launch_bounds__(256, 8) void fused_mfma_kernel(
    const float* __restrict__ x, const uint4* __restrict__ Ap,
    const float* __restrict__ p4w, float* __restrict__ out)
{
    // Single LDS buffer: bf16 transposed x slice, XOR-swizzled chunks.
    // 21024 B -> 7 blocks/CU (28 waves) vs previous 33280 B (4 blocks).
    __shared__ __attribute__((aligned(16))) unsigned short xT[SMEM_HALFS];

    // XCD-aware swizzle: xcd = b&7; each XCD owns a contiguous 16-row h-chunk
    // per n so epilogue tap rows (h-3, h-1, h+1) hit the home XCD's L2.
    const int b = blockIdx.x;
    const int xcd = b & 7;
    const int i_ = b >> 3;           // 0..511
    const int n = i_ >> 4;           // 0..31
    const int h = xcd * 16 + (i_ & 15);

    const int tid = threadIdx.x;
    const int wave = tid >> 6;
    const int lane = tid & 63;
    const int l16 = lane & 15;
    const int quad = lane >> 4;
    const float* xn = x + (size_t)n * CHW_;

    // Rolling weight-fragment stream (L2-resident, 14 loads/wave total).
    const uint4* ApW = Ap + wave * 64 + lane;
    uint4 bcur = ApW[0];             // kt = 0, issued before staging to hide latency

    // ---- zero pad rows (rows 0..8 and 137..145), dword writes ----
    unsigned int* xz = (unsigned int*)xT;
    #pragma unroll
    for (int i = 0; i < 3; ++i) {
        int idx = i * 256 + tid;
        if (idx < 648) {
            int d = (idx < 324) ? idx : (4932 + (idx - 324));
            xz[d] = 0u;
        }
    }

    // ---- stage x[.,h,:] transposed into xT, bf16, packed dword writes ----
    // Swizzle: chunk' = (c>>3) ^ ((row>>1)&7). Write banks spread 16-wide
    // (vs 2 before); read-side b128 stays at the conflict-free minimum since
    // 16*wt drops out of (row>>1)&7.
    const float* xrow = xn + h * W_;
    const int w4 = tid & 31;
    const int cidx = tid >> 5;          // 0..7
    #pragma unroll
    for (int k = 0; k < 4; ++k) {
        const int c0 = k * 16 + cidx * 2;          // even, covers 0..62
        const float* pr = xrow + c0 * HW_ + w4 * 4;
        float4 v0 = *(const float4*)(pr);
        float4 v1 = *(const float4*)(pr + HW_);
        const int chunk = c0 >> 3;
        const int wi = c0 & 7;                     // even -> dword aligned
        float a0[4] = {v0.x, v0.y, v0.z, v0.w};
        float a1[4] = {v1.x, v1.y, v1.z, v1.w};
        #pragma unroll
        for (int j = 0; j < 4; ++j) {
            const int row = w4 * 4 + 9 + j;
            const int s = (row >> 1) & 7;
            unsigned int pk = (unsigned int)f2bf(a0[j]) | ((unsigned int)f2bf(a1[j]) << 16);
            *(unsigned int*)&xT[row * XT_STRIDE + ((chunk ^ s) << 3) + wi] = pk;
        }
    }

    __syncthreads();

    // ---- MFMA K-loop, operand-swapped: A = x-frag (m=w), B = W-frag (n=o) ----
    // C/D: col(l16) = o, row(quad*4+r) = w  ->  lane owns float4 of consecutive w.
    floatx4 acc[8];
    #pragma unroll
    for (int wt = 0; wt < 8; ++wt) acc[wt] = (floatx4){0.f, 0.f, 0.f, 0.f};

    #pragma unroll
    for (int kt = 0; kt < 14; ++kt) {
        const int ktn = (kt < 13) ? (kt + 1) : 13;
        uint4 bnext = ApW[ktn * 256];
        bf16x8 bv = __builtin_bit_cast(bf16x8, bcur);
        const int t = kt >> 1;
        const int row0 = l16 + 3 * t;
        const int s = (row0 >> 1) & 7;
        const int cc = (quad ^ s) ^ ((kt & 1) << 2);
        const unsigned short* pb = &xT[row0 * XT_STRIDE + (cc << 3)];
        #pragma unroll
        for (int wt = 0; wt < 8; ++wt) {
            uint4 d = *(const uint4*)(pb + wt * 16 * XT_STRIDE);  // ds_read_b128
            acc[wt] = __builtin_amdgcn_mfma_f32_16x16x32_bf16(
                __builtin_bit_cast(bf16x8, d), bv, acc[wt], 0, 0, 0);
        }
        bcur = bnext;
    }

    // ---- epilogue: no LDS round-trip, no 2nd barrier; direct float4 stores ----
    const float p0 = p4w[0], p1 = p4w[1], p2 = p4w[2];
    const int h1 = (h - 1) & 127;
    const int o = wave * 16 + l16;
    const float* xc = xn + (size_t)o * HW_;
    const float* xh = xc + h * W_;
    float* oc = out + (size_t)n * CHW_ + (size_t)o * HW_ + h * W_;

    const int hh0 = h1 - 2;
    const int hh2 = h1 + 2;
    const bool g0 = (hh0 >= 0);
    const bool g2 = (hh2 < H_);
    const float* r0p = xc + hh0 * W_;
    const float* r1p = xc + h1 * W_;
    const float* r2p = xc + hh2 * W_;

    #pragma unroll
    for (int wt = 0; wt < 8; ++wt) {
        const int w0 = wt * 16 + quad * 4;
        float4 xv = *(const float4*)(xh + w0);
        const int wsa = w0 + 2;              // <= 126, no wrap
        const int wsb = (w0 + 4) & 127;      // wraps only at w0 = 124
        float t0[4], t1[4], t2[4];
        if (g0) {
            float2 a = *(const float2*)(r0p + wsa);
            float2 b2 = *(const float2*)(r0p + wsb);
            t0[0] = a.x; t0[1] = a.y; t0[2] = b2.x; t0[3] = b2.y;
        } else { t0[0] = t0[1] = t0[2] = t0[3] = 0.f; }
        {
            float2 a = *(const float2*)(r1p + wsa);
            float2 b2 = *(const float2*)(r1p + wsb);
            t1[0] = a.x; t1[1] = a.y; t1[2] = b2.x; t1[3] = b2.y;
        }
        if (g2) {
            float2 a = *(const float2*)(r2p + wsa);
            float2 b2 = *(const float2*)(r2p + wsb);
            t2[0] = a.x; t2[1] = a.y; t2[2] = b2.x; t2[3] = b2.y;
        } else { t2[0] = t2[1] = t2[2] = t2[3] = 0.f; }

        float xa[4] = {xv.x, xv.y, xv.z, xv.w};
        float rr[4];
        #pragma unroll
        for (int e = 0; e < 4; ++e) {
            float t4 = p0 * t0[e] + p1 * t1[e] + p2 * t2[e];
            rr[e] = (xa[e] + acc[wt][e]) * t4;
        }
        *(float4*)(oc + w0) = make_float4(rr[0], rr[1], rr[2], rr[3]);
    }
}

extern "C" void kernel_launch(void* const* d_in, const int* in_sizes, int n_in,
                              void* d_out, int out_size, void* d_ws, size_t ws_size,
                              hipStream_t stream) {
    const float* x   = (const float*)d_in[0];
    const float* Wc  = (const float*)d_in[1];
    const float* p4w = (const float*)d_in[2];
    float* out       = (float*)d_out;
    uint4* Apack     = (uint4*)d_ws;   // 14*4*64*16 = 57344 B

    prepack_kernel<<<14, 256, 0, stream>>>(Wc, Apack);
    fused_mfma_kernel<<<N_ * H_, 256, 0, stream>>>(x, Apack, p4w, out);
}

// Round 3
// 265.299 us; speedup vs baseline: 1.2572x; 1.2572x over previous
//
#include <hip/hip_runtime.h>
#include <hip/hip_bf16.h>

#define N_ 32
#define C_ 64
#define H_ 128
#define W_ 128
#define HW_ (H_ * W_)
#define CHW_ (C_ * HW_)

#define XT_STRIDE 72           // halfs per row (144 B, 16B-aligned); row = w+9, col = channel
#define XT_ROWS 146
#define CB_STRIDE 130          // floats per conv-buffer row (16 rows per wave)
#define SMEM_BYTES (4 * 16 * CB_STRIDE * 4)   // 33280 >= 146*72*2 = 21024

typedef __bf16 bf16x8 __attribute__((ext_vector_type(8)));
typedef float floatx4 __attribute__((ext_vector_type(4)));

__device__ inline unsigned short f2bf(float f) {
    __hip_bfloat16 h = __float2bfloat16(f);
    return *reinterpret_cast<unsigned short*>(&h);
}

// Pre-pack weights into MFMA A-fragment order (bf16).
// A[o][k], k = t*64 + i, from Wc[o*448 + i*7 + t].
__global__ void prepack_kernel(const float* __restrict__ Wc, uint4* __restrict__ Ap) {
    int idx = blockIdx.x * 256 + threadIdx.x;
    if (idx >= 14 * 4 * 64) return;
    int lane = idx & 63;
    int mt = (idx >> 6) & 3;
    int kt = idx >> 8;
    int m = mt * 16 + (lane & 15);
    int kbase = kt * 32 + (lane >> 4) * 8;
    unsigned int r[4];
    #pragma unroll
    for (int p = 0; p < 4; ++p) {
        unsigned int half[2];
        #pragma unroll
        for (int jj = 0; jj < 2; ++jj) {
            int k = kbase + 2 * p + jj;
            int t = k >> 6;
            int i = k & 63;
            half[jj] = f2bf(Wc[m * 448 + i * 7 + t]);
        }
        r[p] = half[0] | (half[1] << 16);
    }
    Ap[idx] = make_uint4(r[0], r[1], r[2], r[3]);
}

__global__ __launch_bounds__(256) void fused_mfma_kernel(
    const float* __restrict__ x, const uint4* __restrict__ Ap,
    const float* __restrict__ p4w, float* __restrict__ out)
{
    // xT (bf16 staging, 21 KB) and convbuf (fp32, 33 KB) are never live
    // simultaneously: union them. LDS 33280 B -> 4 blocks/CU.
    __shared__ __attribute__((aligned(16))) char smem[SMEM_BYTES];
    unsigned short* xT = (unsigned short*)smem;
    float* convbuf = (float*)smem;

    // XCD-aware swizzle: xcd = b&7 (round-robin dispatch). Each XCD owns a
    // contiguous 16-row h-chunk per n, so epilogue tap rows (h-3,h-1,h+1)
    // hit the home XCD's L2 instead of re-fetching from HBM.
    const int b = blockIdx.x;
    const int xcd = b & 7;
    const int i_ = b >> 3;           // 0..511
    const int n = i_ >> 4;           // 0..31
    const int h = xcd * 16 + (i_ & 15);

    const int tid = threadIdx.x;
    const int wave = tid >> 6;
    const int lane = tid & 63;
    const int l16 = lane & 15;
    const int quad = lane >> 4;
    const float* xn = x + (size_t)n * CHW_;

    // ---- load this wave's 14 A fragments first (independent, hides latency) ----
    uint4 afrag[14];
    #pragma unroll
    for (int kt = 0; kt < 14; ++kt)
        afrag[kt] = Ap[kt * 256 + wave * 64 + lane];

    // ---- zero pad rows (rows 0..8 and 137..145), dword writes ----
    // rows 0..8 = dwords [0,324); rows 137..145 = dwords [4932,5256)
    unsigned int* xz = (unsigned int*)xT;
    for (int i = tid; i < 648; i += 256) {
        int d = (i < 324) ? i : (4932 + (i - 324));
        xz[d] = 0u;
    }

    // ---- stage x row-h slice into xT (transposed, bf16) ----
    // Scalar coalesced loads: per pass, wave-uniform c0 (8 channels), w = lane
    // + const -> each of the 8 dword loads is one 256B fully-coalesced
    // transaction. Lane packs 8 consecutive c into ONE ds_write_b128 at
    // xT[(w+9)*72 + c0]. Write bank-group = (w+9 + c0/8) & 7; 64 consecutive
    // w -> 8 lanes/group -> conflict-free (vs 16-way-conflicted scalar u16
    // writes before).
    const float* xrow = xn + h * W_;
    #pragma unroll
    for (int p = 0; p < 4; ++p) {
        const int c0 = wave * 8 + (p >> 1) * 32;       // 0,8,16,24,32,...,56
        const int w = (tid & 63) + (p & 1) * 64;       // 0..127
        const float* src = xrow + (size_t)c0 * HW_ + w;
        unsigned int pk[4];
        #pragma unroll
        for (int i = 0; i < 4; ++i) {
            float f0 = src[(size_t)(2 * i) * HW_];
            float f1 = src[(size_t)(2 * i + 1) * HW_];
            pk[i] = (unsigned int)f2bf(f0) | ((unsigned int)f2bf(f1) << 16);
        }
        *(uint4*)&xT[(w + 9) * XT_STRIDE + c0] = make_uint4(pk[0], pk[1], pk[2], pk[3]);
    }

    __syncthreads();

    // ---- MFMA K-loop: O[o0+16][128] for o0 = wave*16 ----
    // B-read bank-group = (row + chunk) & 7 (stride 144B, 9 = 1 mod 8):
    // l16 x quad covers each group 8x -> conflict-free ds_read_b128.
    floatx4 acc[8];
    #pragma unroll
    for (int nt = 0; nt < 8; ++nt) acc[nt] = (floatx4){0.f, 0.f, 0.f, 0.f};

    const int base_half = l16 * XT_STRIDE + quad * 8;
    #pragma unroll
    for (int kt = 0; kt < 14; ++kt) {
        bf16x8 av = __builtin_bit_cast(bf16x8, afrag[kt]);
        int koff = (kt >> 1) * 3 * XT_STRIDE + (kt & 1) * 32;
        #pragma unroll
        for (int nt = 0; nt < 8; ++nt) {
            int off = base_half + koff + nt * 16 * XT_STRIDE;
            uint4 d = *(const uint4*)&xT[off];           // ds_read_b128, 16B-aligned
            bf16x8 bv = __builtin_bit_cast(bf16x8, d);
            acc[nt] = __builtin_amdgcn_mfma_f32_16x16x32_bf16(av, bv, acc[nt], 0, 0, 0);
        }
    }

    // xT is dead past here; convbuf aliases it — barrier before reuse.
    __syncthreads();

    // ---- round-trip conv result through LDS (wave-private area) ----
    // Write banks: (8*quad + 2*r + l16) % 32 -> worst 2-way (free).
    float* cw = convbuf + wave * 16 * CB_STRIDE;
    #pragma unroll
    for (int nt = 0; nt < 8; ++nt) {
        #pragma unroll
        for (int r = 0; r < 4; ++r)
            cw[(quad * 4 + r) * CB_STRIDE + nt * 16 + l16] = acc[nt][r];
    }

    // ---- epilogue: t4 + fuse + coalesced float4 stores ----
    const float p0 = p4w[0], p1 = p4w[1], p2 = p4w[2];
    const int h1 = (h - 1 + H_) & 127;

    #pragma unroll
    for (int j = 0; j < 8; ++j) {
        int idx = j * 64 + lane;           // 0..511
        int o_ = idx >> 5;                 // 0..15
        int w4 = idx & 31;
        int w = w4 * 4;
        int o = wave * 16 + o_;

        float4 cv = *(const float4*)&cw[o_ * CB_STRIDE + w];

        const float* xc = xn + o * HW_;
        float4 xv = *(const float4*)(xc + h * W_ + w);

        int wsrc = w + 2;
        float tap[3][4];
        #pragma unroll
        for (int k = 0; k < 3; ++k) {
            int hh = h1 + 2 * k - 2;
            if (hh >= 0 && hh < H_) {
                const float* rowp = xc + hh * W_;
                float2 a = *(const float2*)(rowp + wsrc);
                float2 b2 = *(const float2*)(rowp + ((wsrc + 2) & 127));
                tap[k][0] = a.x; tap[k][1] = a.y; tap[k][2] = b2.x; tap[k][3] = b2.y;
            } else {
                tap[k][0] = tap[k][1] = tap[k][2] = tap[k][3] = 0.f;
            }
        }
        float ov[4];
        float xa[4] = {xv.x, xv.y, xv.z, xv.w};
        float ca[4] = {cv.x, cv.y, cv.z, cv.w};
        #pragma unroll
        for (int e = 0; e < 4; ++e) {
            float t4 = p0 * tap[0][e] + p1 * tap[1][e] + p2 * tap[2][e];
            ov[e] = (xa[e] + ca[e]) * t4;
        }
        *(float4*)(out + (size_t)n * CHW_ + o * HW_ + h * W_ + w) =
            make_float4(ov[0], ov[1], ov[2], ov[3]);
    }
}

extern "C" void kernel_launch(void* const* d_in, const int* in_sizes, int n_in,
                              void* d_out, int out_size, void* d_ws, size_t ws_size,
                              hipStream_t stream) {
    const float* x   = (const float*)d_in[0];
    const float* Wc  = (const float*)d_in[1];
    const float* p4w = (const float*)d_in[2];
    float* out       = (float*)d_out;
    uint4* Apack     = (uint4*)d_ws;   // 14*4*64*16 = 57344 B

    prepack_kernel<<<14, 256, 0, stream>>>(Wc, Apack);
    fused_mfma_kernel<<<N_ * H_, 256, 0, stream>>>(x, Apack, p4w, out);
}